// Round 5
// baseline (581.632 us; speedup 1.0000x reference)
//
#include <hip/hip_runtime.h>
#include <hip/hip_fp16.h>

#define BB 4
#define HH 240
#define WW 1216
#define NIMG (HH * WW)
#define NPIX (BB * NIMG)          // 1,167,360
#define GRID_PRE (NPIX / 256)     // 4560

// padded feat layout: image pixel (y,x) lives at (y+2, x+2); 5x5 window of
// pixel (y,x) starts at padded (y, x). Pad cells only ever get weight 0.
#define HHP (HH + 4)              // 244
#define WWP (WW + 4)              // 1220
#define PIMG (HHP * WWP)

// confidence padded with 2 zero rows/cols each side (+1 slack bottom/right)
#define CHP 245
#define CWP 1221
#define CIMG (CHP * CWP)

#define OVF_CAP 65536

// fused 2-step tiling
#define TSX 32                    // B tile width
#define TSY 30                    // B tile height (240 = 8*30 exact)
#define ARX 36                    // A region cols = TSX+4
#define ARY 34                    // A region rows = TSY+4
#define LSTR 38                   // LDS row stride (floats, even)
#define NTX (WW / TSX)            // 38
#define NTY (HH / TSY)            // 8
#define NTILES (NTX * NTY * BB)   // 1216

typedef __attribute__((ext_vector_type(2))) float float2v;

struct OvfEntry {                 // exception pixel: full 9-tap data
    int p;
    int base[9];                  // padded-layout corner base indices
    float w[36];                  // 4 premultiplied fp32 weights per tap
};

__device__ __forceinline__ unsigned f2h(float f) {
    union { _Float16 h; unsigned short u; } cv;
    cv.h = (_Float16)f;
    return (unsigned)cv.u;
}
__device__ __forceinline__ float h2f(unsigned u) {
    union { unsigned short u; _Float16 h; } cv;
    cv.u = (unsigned short)(u & 0xffffu);
    return (float)cv.h;
}

// ---------------------------------------------------------------------------
__global__ __launch_bounds__(256) void k_permute(const float* __restrict__ W_oa,
                                                 float* __restrict__ Wre) {
    for (int i = threadIdx.x; i < 24 * 8 * 9; i += 256) {
        int o = i / 72;
        int r = i - o * 72;
        int c = r / 9;
        int t = r - c * 9;
        Wre[(c * 9 + t) * 24 + o] = W_oa[i];
    }
}

__global__ __launch_bounds__(256) void k_padconf(const float* __restrict__ conf,
                                                 float* __restrict__ cpad) {
    int i = blockIdx.x * 256 + threadIdx.x;
    if (i >= BB * CIMG) return;
    int xp = i % CWP;
    int yp = (i / CWP) % CHP;
    int b = i / CIMG;
    float v = 0.f;
    int y = yp - 2, x = xp - 2;
    if (y >= 0 && y < HH && x >= 0 && x < WW) v = conf[b * NIMG + y * WW + x];
    cpad[i] = v;
}

__device__ __forceinline__ float fast_tanh(float x) {
    float xc = fminf(fmaxf(x, -15.f), 15.f);
    float e = __expf(2.f * xc);
    return 1.f - 2.f * __builtin_amdgcn_rcpf(e + 1.f);
}

// conv helper: 8->24ch 3x3, packed-f32 accumulators. GUARD = border checks.
template <bool GUARD>
__device__ __forceinline__ void conv_accum(const float* __restrict__ gb,
                                           int y, int x,
                                           const float* __restrict__ Wre,
                                           float2v* acc2) {
#pragma unroll 1
    for (int c = 0; c < 8; c++) {
        const float* gc = gb + c * NIMG;
#pragma unroll
        for (int t = 0; t < 9; t++) {
            int dy = t / 3 - 1;
            int dx = t - (t / 3) * 3 - 1;
            float gv;
            if (GUARD) {
                int yy = y + dy, xx = x + dx;
                gv = (yy >= 0 && yy < HH && xx >= 0 && xx < WW)
                         ? gc[yy * WW + xx] : 0.f;
            } else {
                gv = gc[(y + dy) * WW + (x + dx)];
            }
            const float2v* w2 = (const float2v*)(Wre + (c * 9 + t) * 24);
            float2v g2 = {gv, gv};
#pragma unroll
            for (int o = 0; o < 12; o++)
                acc2[o] = __builtin_elementwise_fma(g2, w2[o], acc2[o]);
        }
    }
}

// ---------------------------------------------------------------------------
// Precompute: conv head -> affinities -> dense 5x5 window weights built in
// REGISTERS via separable outer-product accumulation (no LDS, static idx).
// Exception flag plane encodes (ovf index + 1) << 16.
// ---------------------------------------------------------------------------
__global__ __launch_bounds__(256) void k_precompute(
    const float* __restrict__ guid, const float* __restrict__ cpad,
    const float* __restrict__ feat_init, const float* __restrict__ feat_fix,
    const float* __restrict__ Wre, const float* __restrict__ b_oa,
    const float* __restrict__ aff_scale,
    float* __restrict__ F0, unsigned* __restrict__ Wt,
    OvfEntry* __restrict__ ovf, int* __restrict__ ovf_cnt) {
    int p = blockIdx.x * 256 + threadIdx.x;
    int x = p % WW;
    int y = (p / WW) % HH;
    int b = p / NIMG;

    // ---- 3x3 conv, 8 in-ch -> 24 out-ch, zero pad (packed f32) ----
    float2v acc2[12];
    const float2v* b2 = (const float2v*)b_oa;
#pragma unroll
    for (int o = 0; o < 12; o++) acc2[o] = b2[o];

    const float* gb = guid + (size_t)b * 8 * NIMG;
    bool interior = (y >= 1) && (y <= HH - 2) && (x >= 1) && (x <= WW - 2);
    if (interior) conv_accum<false>(gb, y, x, Wre, acc2);
    else          conv_accum<true>(gb, y, x, Wre, acc2);

    float acc[24];
#pragma unroll
    for (int o = 0; o < 24; o++)
        acc[o] = (o & 1) ? acc2[o >> 1].y : acc2[o >> 1].x;

    // ---- TGASS affinity + confidence modulation ----
    float inv_ascale = __builtin_amdgcn_rcpf(aff_scale[0] + 1e-8f);
    const float* cb = cpad + (size_t)b * CIMG;
    float aff[8], ofy[8], ofx[8];
    float asum = 0.f;
#pragma unroll
    for (int k = 0; k < 8; k++) {
        float dy = acc[k];
        float dx = acc[8 + k];
        ofy[k] = dy;
        ofx[k] = dx;
        float a = fast_tanh(acc[16 + k]) * inv_ascale;
        float ys = dy + (float)y;
        float xs = dx + (float)x;
        float y0f = floorf(ys), x0f = floorf(xs);
        float wy = ys - y0f, wx = xs - x0f;
        int ya = (int)(fminf(fmaxf(y0f, -2.f), 241.f)) + 2;
        int yb = (int)(fminf(fmaxf(y0f + 1.f, -2.f), 241.f)) + 2;
        int xa = (int)(fminf(fmaxf(x0f, -2.f), 1217.f)) + 2;
        int xb = (int)(fminf(fmaxf(x0f + 1.f, -2.f), 1217.f)) + 2;
        float v00 = cb[ya * CWP + xa];
        float v01 = cb[ya * CWP + xb];
        float v10 = cb[yb * CWP + xa];
        float v11 = cb[yb * CWP + xb];
        float v = (v00 * (1.f - wx) + v01 * wx) * (1.f - wy)
                + (v10 * (1.f - wx) + v11 * wx) * wy;
        a *= v;
        aff[k] = a;
        asum += fabsf(a);
    }

    float s = fmaxf(asum + 1e-4f, 1.0f);
    float inv = __builtin_amdgcn_rcpf(s);
    float tot = 0.f;
#pragma unroll
    for (int k = 0; k < 8; k++) {
        aff[k] *= inv;
        tot += aff[k];
    }
    float aref = 1.0f - tot;

    // ---- register 5x5 window: separable outer-product accumulation ----
    float w[25];
#pragma unroll
    for (int i = 0; i < 25; i++) w[i] = 0.f;
    bool fits = true;
#pragma unroll
    for (int kk = 0; kk < 9; kk++) {
        float a, dy, dx;
        if (kk < 4)       { a = aff[kk];     dy = ofy[kk];     dx = ofx[kk]; }
        else if (kk == 4) { a = aref;        dy = 0.f;         dx = 0.f; }
        else              { a = aff[kk - 1]; dy = ofy[kk - 1]; dx = ofx[kk - 1]; }
        const int kh = kk / 3 - 1;
        const int kw = kk - (kk / 3) * 3 - 1;
        float fly = floorf(dy), flx = floorf(dx);
        fits = fits && (fly >= -1.f) && (fly <= 0.f)
                    && (flx >= -1.f) && (flx <= 0.f);
        float wy = dy - fly, wx = dx - flx;
        float byf = fly + 1.f, bxf = flx + 1.f;     // in {0,1} on fast path
        int y0 = y + kh + (int)fly;
        int x0 = x + kw + (int)flx;
        float cy0 = (y0 >= 0 && y0 <= HH - 1) ? (1.f - wy) : 0.f;
        float cy1 = (y0 + 1 >= 0 && y0 + 1 <= HH - 1) ? wy : 0.f;
        float cx0 = (x0 >= 0 && x0 <= WW - 1) ? (1.f - wx) : 0.f;
        float cx1 = (x0 + 1 >= 0 && x0 + 1 <= WW - 1) ? wx : 0.f;
        float cya0 = cy0 * a, cya1 = cy1 * a;
        float ry0 = cya0 - byf * cya0;
        float ry1 = fmaf(byf, cya0, cya1 - byf * cya1);
        float ry2 = byf * cya1;
        float rx0 = cx0 - bxf * cx0;
        float rx1 = fmaf(bxf, cx0, cx1 - bxf * cx1);
        float rx2 = bxf * cx1;
        const int base = (kh + 1) * 5 + (kw + 1);   // compile-time
        w[base + 0]  = fmaf(ry0, rx0, w[base + 0]);
        w[base + 1]  = fmaf(ry0, rx1, w[base + 1]);
        w[base + 2]  = fmaf(ry0, rx2, w[base + 2]);
        w[base + 5]  = fmaf(ry1, rx0, w[base + 5]);
        w[base + 6]  = fmaf(ry1, rx1, w[base + 6]);
        w[base + 7]  = fmaf(ry1, rx2, w[base + 7]);
        w[base + 10] = fmaf(ry2, rx0, w[base + 10]);
        w[base + 11] = fmaf(ry2, rx1, w[base + 11]);
        w[base + 12] = fmaf(ry2, rx2, w[base + 12]);
    }

    float yf = (float)y, xf = (float)x;
    if (fits) {
#pragma unroll
        for (int j = 0; j < 13; j++) {
            unsigned lo = f2h(w[2 * j]);
            unsigned hi = (j < 12) ? f2h(w[2 * j + 1]) : 0u;
            Wt[(size_t)j * NPIX + p] = lo | (hi << 16);
        }
    } else {
        int slot = atomicAdd(ovf_cnt, 1);
        unsigned fl = (slot < OVF_CAP) ? (unsigned)(slot + 1) : 65535u;
        if (slot < OVF_CAP) {
            OvfEntry* e = &ovf[slot];
            e->p = p;
#pragma unroll
            for (int kk = 0; kk < 9; kk++) {
                float a, dy, dx;
                if (kk < 4)       { a = aff[kk];     dy = ofy[kk];     dx = ofx[kk]; }
                else if (kk == 4) { a = aref;        dy = 0.f;         dx = 0.f; }
                else              { a = aff[kk - 1]; dy = ofy[kk - 1]; dx = ofx[kk - 1]; }
                float ys = yf + (float)(kk / 3 - 1) + dy;
                float xs = xf + (float)(kk - (kk / 3) * 3 - 1) + dx;
                float y0f = floorf(ys), x0f = floorf(xs);
                float wy = ys - y0f, wx = xs - x0f;
                float y0c = fminf(fmaxf(y0f, -2.f), (float)HH);
                float x0c = fminf(fmaxf(x0f, -2.f), (float)WW);
                int y0 = (int)y0c, x0 = (int)x0c;
                int by = min(max(y0, 0), HH - 2);
                int bx = min(max(x0, 0), WW - 2);
                float cy0 = 0.f, cy1 = 0.f;
                if (y0 >= 0 && y0 <= HH - 1) { if (y0 == by) cy0 = 1.f - wy; else cy1 = 1.f - wy; }
                if (y0 + 1 >= 0 && y0 + 1 <= HH - 1) { if (y0 + 1 == by) cy0 = wy; else cy1 = wy; }
                float cx0 = 0.f, cx1 = 0.f;
                if (x0 >= 0 && x0 <= WW - 1) { if (x0 == bx) cx0 = 1.f - wx; else cx1 = 1.f - wx; }
                if (x0 + 1 >= 0 && x0 + 1 <= WW - 1) { if (x0 + 1 == bx) cx0 = wx; else cx1 = wx; }
                e->base[kk] = (b * HHP + by + 2) * WWP + bx + 2;
                e->w[kk * 4 + 0] = cy0 * cx0 * a;
                e->w[kk * 4 + 1] = cy0 * cx1 * a;
                e->w[kk * 4 + 2] = cy1 * cx0 * a;
                e->w[kk * 4 + 3] = cy1 * cx1 * a;
            }
        }
#pragma unroll
        for (int j = 0; j < 13; j++)
            Wt[(size_t)j * NPIX + p] = (j == 12) ? (fl << 16) : 0u;
    }

    // ---- F0 = sparse-fix-injected initial feat (padded layout) ----
    float ff = feat_fix[p];
    F0[(b * HHP + y + 2) * WWP + x + 2] = (ff > 0.f) ? ff : feat_init[p];
}

// general 9-tap (exception) raw stencil value from padded Fin
__device__ __forceinline__ float general9(const OvfEntry* __restrict__ e,
                                          const float* __restrict__ Fin) {
    float s = 0.f;
#pragma unroll
    for (int kk = 0; kk < 9; kk++) {
        int base = e->base[kk];
        s = fmaf(Fin[base],           e->w[kk * 4 + 0], s);
        s = fmaf(Fin[base + 1],       e->w[kk * 4 + 1], s);
        s = fmaf(Fin[base + WWP],     e->w[kk * 4 + 2], s);
        s = fmaf(Fin[base + WWP + 1], e->w[kk * 4 + 3], s);
    }
    return s;
}

// step-A (mixed) value of the pixel whose padded index is q; general path.
__device__ float stepA_at(int q, const float* __restrict__ Fin,
                          const unsigned* __restrict__ Wt,
                          const float* __restrict__ feat_fix,
                          const OvfEntry* __restrict__ ovf) {
    int bq = q / PIMG;
    int rem = q - bq * PIMG;
    int yq = rem / WWP - 2;
    int xq = rem % WWP - 2;
    int pq = bq * NIMG + yq * WW + xq;
    unsigned fl = Wt[(size_t)12 * NPIX + pq] >> 16;
    float s;
    if (fl) {
        s = general9(&ovf[fl - 1], Fin);
    } else {
        unsigned u13[13];
#pragma unroll
        for (int j = 0; j < 13; j++) u13[j] = Wt[(size_t)j * NPIX + pq];
        const float* fb = Fin + (q - 2 * WWP - 2);
        s = 0.f;
#pragma unroll
        for (int c = 0; c < 25; c++) {
            const int j = c >> 1, r = c / 5, cc = c - r * 5;
            unsigned uw = (c & 1) ? (u13[j] >> 16) : u13[j];
            s = fmaf(fb[r * WWP + cc], h2f(uw), s);
        }
    }
    float ff = feat_fix[pq];
    return (ff > 0.f) ? ff : s;
}

// ---------------------------------------------------------------------------
// Fused 2-step propagation. Per tile: step-A (36x34 region incl halo) into
// LDS, barrier, step-B (32x30) from LDS. Extra block handles exceptions.
// ---------------------------------------------------------------------------
__global__ __launch_bounds__(256) void k_prop2(
    const float* __restrict__ Fin, const unsigned* __restrict__ Wt,
    const float* __restrict__ feat_fix, const OvfEntry* __restrict__ ovf,
    const int* __restrict__ ovf_cnt, float* __restrict__ Fout, int last) {
    __shared__ float As[ARY * LSTR];
    const int tid = threadIdx.x;
    const int blk = blockIdx.x;

    if (blk == NTILES) {
        // -------- exception pixels: full general 2-step from global Fin ----
        int cnt = *ovf_cnt;
        if (cnt > OVF_CAP) cnt = OVF_CAP;
        for (int i = tid; i < cnt; i += 256) {
            const OvfEntry* e = &ovf[i];
            float sB = 0.f;
#pragma unroll 1
            for (int kk = 0; kk < 9; kk++) {
                int base = e->base[kk];
                sB = fmaf(stepA_at(base,           Fin, Wt, feat_fix, ovf), e->w[kk * 4 + 0], sB);
                sB = fmaf(stepA_at(base + 1,       Fin, Wt, feat_fix, ovf), e->w[kk * 4 + 1], sB);
                sB = fmaf(stepA_at(base + WWP,     Fin, Wt, feat_fix, ovf), e->w[kk * 4 + 2], sB);
                sB = fmaf(stepA_at(base + WWP + 1, Fin, Wt, feat_fix, ovf), e->w[kk * 4 + 3], sB);
            }
            int p = e->p;
            if (last) {
                Fout[p] = sB;
            } else {
                float ff = feat_fix[p];
                int xx = p % WW;
                int yy = (p / WW) % HH;
                int bb = p / NIMG;
                Fout[(bb * HHP + yy + 2) * WWP + xx + 2] = (ff > 0.f) ? ff : sB;
            }
        }
        return;
    }

    const int b = blk / (NTX * NTY);
    const int tr = blk - b * (NTX * NTY);
    const int tiley = (tr / NTX) * TSY;
    const int tilex = (tr - (tr / NTX) * NTX) * TSX;

    // ---------------- step A: 36x34 region (2-px pairs) into LDS ----------
#pragma unroll 1
    for (int q = tid; q < ARY * (ARX / 2); q += 256) {
        int ar = q / (ARX / 2);
        int ac2 = (q - ar * (ARX / 2)) * 2;
        int ya = tiley - 2 + ar;
        int xa = tilex - 2 + ac2;
        float s0 = 0.f, s1 = 0.f;
        if (ya >= 0 && ya < HH && xa >= 0 && xa < WW) {
            int p = b * NIMG + ya * WW + xa;
            uint2 w2[13];
#pragma unroll
            for (int j = 0; j < 13; j++)
                w2[j] = *(const uint2*)&Wt[(size_t)j * NPIX + p];
            const float* fb = Fin + (size_t)(b * HHP + ya) * WWP + xa;
            float f[5][6];
#pragma unroll
            for (int r = 0; r < 5; r++) {
                const float* row = fb + r * WWP;
                float2v a0 = *(const float2v*)(row);
                float2v a1 = *(const float2v*)(row + 2);
                float2v a2 = *(const float2v*)(row + 4);
                f[r][0] = a0.x; f[r][1] = a0.y;
                f[r][2] = a1.x; f[r][3] = a1.y;
                f[r][4] = a2.x; f[r][5] = a2.y;
            }
#pragma unroll
            for (int c = 0; c < 25; c++) {
                const int j = c >> 1, r = c / 5, cc = c - r * 5;
                unsigned a0 = (c & 1) ? (w2[j].x >> 16) : w2[j].x;
                unsigned a1 = (c & 1) ? (w2[j].y >> 16) : w2[j].y;
                s0 = fmaf(f[r][cc],     h2f(a0), s0);
                s1 = fmaf(f[r][cc + 1], h2f(a1), s1);
            }
            unsigned flag0 = w2[12].x >> 16;
            unsigned flag1 = w2[12].y >> 16;
            if (flag0) s0 = general9(&ovf[flag0 - 1], Fin);
            if (flag1) s1 = general9(&ovf[flag1 - 1], Fin);
            float2v ff = *(const float2v*)&feat_fix[p];
            s0 = (ff.x > 0.f) ? ff.x : s0;          // A is never the last step
            s1 = (ff.y > 0.f) ? ff.y : s1;
        }
        As[ar * LSTR + ac2] = s0;
        As[ar * LSTR + ac2 + 1] = s1;
    }

    // ---------------- step B: prefetch Wt/fix, barrier, compute -----------
    const int ty = tid >> 3;                // 0..31
    const int qx = tid & 7;
    const bool bvalid = (ty < TSY);
    const int yb = tiley + ty;
    const int xb = tilex + (qx << 2);
    const int pB = b * NIMG + yb * WW + xb;
    uint4 u[13];
    float4 fix4;
    if (bvalid) {
#pragma unroll
        for (int j = 0; j < 13; j++)
            u[j] = *(const uint4*)&Wt[(size_t)j * NPIX + pB];
        fix4 = *(const float4*)&feat_fix[pB];
    }
    __syncthreads();

    if (!bvalid) return;

    float f[5][8];
    const float* As0 = As + ty * LSTR + (qx << 2);
#pragma unroll
    for (int r = 0; r < 5; r++) {
        const float* row = As0 + r * LSTR;
        float2v a0 = *(const float2v*)(row);
        float2v a1 = *(const float2v*)(row + 2);
        float2v a2 = *(const float2v*)(row + 4);
        float2v a3 = *(const float2v*)(row + 6);
        f[r][0] = a0.x; f[r][1] = a0.y; f[r][2] = a1.x; f[r][3] = a1.y;
        f[r][4] = a2.x; f[r][5] = a2.y; f[r][6] = a3.x; f[r][7] = a3.y;
    }

    float s0 = 0.f, s1 = 0.f, s2 = 0.f, s3 = 0.f;
#pragma unroll
    for (int c = 0; c < 25; c++) {
        const int j = c >> 1, r = c / 5, cc = c - r * 5;
        unsigned e0 = (c & 1) ? (u[j].x >> 16) : u[j].x;
        unsigned e1 = (c & 1) ? (u[j].y >> 16) : u[j].y;
        unsigned e2 = (c & 1) ? (u[j].z >> 16) : u[j].z;
        unsigned e3 = (c & 1) ? (u[j].w >> 16) : u[j].w;
        s0 = fmaf(f[r][cc],     h2f(e0), s0);
        s1 = fmaf(f[r][cc + 1], h2f(e1), s1);
        s2 = fmaf(f[r][cc + 2], h2f(e2), s2);
        s3 = fmaf(f[r][cc + 3], h2f(e3), s3);
    }
    unsigned fl0 = u[12].x >> 16, fl1 = u[12].y >> 16;
    unsigned fl2 = u[12].z >> 16, fl3 = u[12].w >> 16;
    bool anyflag = (fl0 | fl1 | fl2 | fl3) != 0;

    if (last) {
        if (!anyflag) {
            float4 o = {s0, s1, s2, s3};
            *(float4*)&Fout[pB] = o;
        } else {                   // flagged pixels written by exception block
            if (!fl0) Fout[pB] = s0;
            if (!fl1) Fout[pB + 1] = s1;
            if (!fl2) Fout[pB + 2] = s2;
            if (!fl3) Fout[pB + 3] = s3;
        }
    } else {
        float o0 = (fix4.x > 0.f) ? fix4.x : s0;
        float o1 = (fix4.y > 0.f) ? fix4.y : s1;
        float o2 = (fix4.z > 0.f) ? fix4.z : s2;
        float o3 = (fix4.w > 0.f) ? fix4.w : s3;
        float* po = Fout + (size_t)(b * HHP + yb + 2) * WWP + xb + 2;
        if (!anyflag) {
            float2v w01 = {o0, o1};
            float2v w23 = {o2, o3};
            *(float2v*)(po) = w01;
            *(float2v*)(po + 2) = w23;
        } else {
            if (!fl0) po[0] = o0;
            if (!fl1) po[1] = o1;
            if (!fl2) po[2] = o2;
            if (!fl3) po[3] = o3;
        }
    }
}

extern "C" void kernel_launch(void* const* d_in, const int* in_sizes, int n_in,
                              void* d_out, int out_size, void* d_ws, size_t ws_size,
                              hipStream_t stream) {
    const float* feat_init  = (const float*)d_in[0];
    const float* guidance   = (const float*)d_in[1];
    const float* confidence = (const float*)d_in[2];
    const float* feat_fix   = (const float*)d_in[3];
    const float* W_oa       = (const float*)d_in[4];
    const float* b_oa       = (const float*)d_in[5];
    const float* aff_scale  = (const float*)d_in[6];

    char* ws = (char*)d_ws;
    size_t off = 0;
    auto carve = [&](size_t bytes) -> char* {
        char* ptr = ws + off;
        off += (bytes + 511) & ~(size_t)511;
        return ptr;
    };
    float*    Wre  = (float*)carve(24 * 8 * 9 * sizeof(float));
    float*    CPAD = (float*)carve((size_t)BB * CIMG * sizeof(float));
    float*    F0   = (float*)carve((size_t)BB * PIMG * sizeof(float));
    float*    F1   = (float*)carve((size_t)BB * PIMG * sizeof(float));
    unsigned* Wt   = (unsigned*)carve((size_t)13 * NPIX * sizeof(unsigned));
    OvfEntry* OVF  = (OvfEntry*)carve((size_t)OVF_CAP * sizeof(OvfEntry));
    int*      CNT  = (int*)carve(sizeof(int));
    (void)ws_size; (void)in_sizes; (void)n_in; (void)out_size;

    hipMemsetAsync(CNT, 0, sizeof(int), stream);

    int gridc = (BB * CIMG + 255) / 256;
    hipLaunchKernelGGL(k_permute, dim3(1), dim3(256), 0, stream, W_oa, Wre);
    hipLaunchKernelGGL(k_padconf, dim3(gridc), dim3(256), 0, stream,
                       confidence, CPAD);
    hipLaunchKernelGGL(k_precompute, dim3(GRID_PRE), dim3(256), 0, stream,
                       guidance, CPAD, feat_init, feat_fix, Wre, b_oa,
                       aff_scale, F0, Wt, OVF, CNT);

    float* bufs[2] = {F0, F1};
    int cur = 0;
    for (int it = 0; it < 9; ++it) {
        int last = (it == 8) ? 1 : 0;
        float* outp = last ? (float*)d_out : bufs[cur ^ 1];
        hipLaunchKernelGGL(k_prop2, dim3(NTILES + 1), dim3(256), 0, stream,
                           bufs[cur], Wt, feat_fix, OVF, CNT, outp, last);
        cur ^= 1;
    }
}

// Round 6
// 467.407 us; speedup vs baseline: 1.2444x; 1.2444x over previous
//
#include <hip/hip_runtime.h>
#include <hip/hip_fp16.h>

#define BB 4
#define HH 240
#define WW 1216
#define NIMG (HH * WW)
#define NPIX (BB * NIMG)          // 1,167,360
#define GRID_PRE (NPIX / 256)     // 4560
#define GRID_PROP (NPIX / 1024)   // 1140 (4 pixels per thread)

// padded feat layout: image pixel (y,x) lives at (y+2, x+2); 5x5 window of
// pixel (y,x) starts at padded (y, x). Pad cells only ever get weight 0.
#define HHP (HH + 4)              // 244
#define WWP (WW + 4)              // 1220
#define PIMG (HHP * WWP)

// confidence padded with 2 zero rows/cols each side (+1 slack bottom/right)
#define CHP 245
#define CWP 1221
#define CIMG (CHP * CWP)

#define OVF_CAP 65536

typedef __attribute__((ext_vector_type(2))) float float2v;

struct OvfEntry {                 // exception pixel: full 9-tap data
    int p;
    int base[9];                  // padded-layout corner base indices
    float w[36];                  // 4 premultiplied fp32 weights per tap
};

__device__ __forceinline__ unsigned f2h(float f) {
    union { _Float16 h; unsigned short u; } cv;
    cv.h = (_Float16)f;
    return (unsigned)cv.u;
}
__device__ __forceinline__ float h2f(unsigned u) {
    union { unsigned short u; _Float16 h; } cv;
    cv.u = (unsigned short)(u & 0xffffu);
    return (float)cv.h;
}

// ---------------------------------------------------------------------------
__global__ __launch_bounds__(256) void k_permute(const float* __restrict__ W_oa,
                                                 float* __restrict__ Wre) {
    for (int i = threadIdx.x; i < 24 * 8 * 9; i += 256) {
        int o = i / 72;
        int r = i - o * 72;
        int c = r / 9;
        int t = r - c * 9;
        Wre[(c * 9 + t) * 24 + o] = W_oa[i];
    }
}

__global__ __launch_bounds__(256) void k_padconf(const float* __restrict__ conf,
                                                 float* __restrict__ cpad) {
    int i = blockIdx.x * 256 + threadIdx.x;
    if (i >= BB * CIMG) return;
    int xp = i % CWP;
    int yp = (i / CWP) % CHP;
    int b = i / CIMG;
    float v = 0.f;
    int y = yp - 2, x = xp - 2;
    if (y >= 0 && y < HH && x >= 0 && x < WW) v = conf[b * NIMG + y * WW + x];
    cpad[i] = v;
}

__device__ __forceinline__ float fast_tanh(float x) {
    float xc = fminf(fmaxf(x, -15.f), 15.f);
    float e = __expf(2.f * xc);
    return 1.f - 2.f * __builtin_amdgcn_rcpf(e + 1.f);
}

// conv helper: 8->24ch 3x3, packed-f32 accumulators. GUARD = border checks.
template <bool GUARD>
__device__ __forceinline__ void conv_accum(const float* __restrict__ gb,
                                           int y, int x,
                                           const float* __restrict__ Wre,
                                           float2v* acc2) {
#pragma unroll 1
    for (int c = 0; c < 8; c++) {
        const float* gc = gb + c * NIMG;
#pragma unroll
        for (int t = 0; t < 9; t++) {
            int dy = t / 3 - 1;
            int dx = t - (t / 3) * 3 - 1;
            float gv;
            if (GUARD) {
                int yy = y + dy, xx = x + dx;
                gv = (yy >= 0 && yy < HH && xx >= 0 && xx < WW)
                         ? gc[yy * WW + xx] : 0.f;
            } else {
                gv = gc[(y + dy) * WW + (x + dx)];
            }
            const float2v* w2 = (const float2v*)(Wre + (c * 9 + t) * 24);
            float2v g2 = {gv, gv};
#pragma unroll
            for (int o = 0; o < 12; o++)
                acc2[o] = __builtin_elementwise_fma(g2, w2[o], acc2[o]);
        }
    }
}

// ---------------------------------------------------------------------------
// Precompute: conv head -> affinities -> dense 5x5 window weights built in
// REGISTERS via separable outer-product accumulation (no LDS, static idx).
// Exception flag plane encodes (ovf index + 1) << 16.
// ---------------------------------------------------------------------------
__global__ __launch_bounds__(256) void k_precompute(
    const float* __restrict__ guid, const float* __restrict__ cpad,
    const float* __restrict__ feat_init, const float* __restrict__ feat_fix,
    const float* __restrict__ Wre, const float* __restrict__ b_oa,
    const float* __restrict__ aff_scale,
    float* __restrict__ F0, unsigned* __restrict__ Wt,
    OvfEntry* __restrict__ ovf, int* __restrict__ ovf_cnt) {
    int p = blockIdx.x * 256 + threadIdx.x;
    int x = p % WW;
    int y = (p / WW) % HH;
    int b = p / NIMG;

    // ---- 3x3 conv, 8 in-ch -> 24 out-ch, zero pad (packed f32) ----
    float2v acc2[12];
    const float2v* b2 = (const float2v*)b_oa;
#pragma unroll
    for (int o = 0; o < 12; o++) acc2[o] = b2[o];

    const float* gb = guid + (size_t)b * 8 * NIMG;
    bool interior = (y >= 1) && (y <= HH - 2) && (x >= 1) && (x <= WW - 2);
    if (interior) conv_accum<false>(gb, y, x, Wre, acc2);
    else          conv_accum<true>(gb, y, x, Wre, acc2);

    float acc[24];
#pragma unroll
    for (int o = 0; o < 24; o++)
        acc[o] = (o & 1) ? acc2[o >> 1].y : acc2[o >> 1].x;

    // ---- TGASS affinity + confidence modulation ----
    float inv_ascale = __builtin_amdgcn_rcpf(aff_scale[0] + 1e-8f);
    const float* cb = cpad + (size_t)b * CIMG;
    float aff[8], ofy[8], ofx[8];
    float asum = 0.f;
#pragma unroll
    for (int k = 0; k < 8; k++) {
        float dy = acc[k];
        float dx = acc[8 + k];
        ofy[k] = dy;
        ofx[k] = dx;
        float a = fast_tanh(acc[16 + k]) * inv_ascale;
        float ys = dy + (float)y;
        float xs = dx + (float)x;
        float y0f = floorf(ys), x0f = floorf(xs);
        float wy = ys - y0f, wx = xs - x0f;
        int ya = (int)(fminf(fmaxf(y0f, -2.f), 241.f)) + 2;
        int yb = (int)(fminf(fmaxf(y0f + 1.f, -2.f), 241.f)) + 2;
        int xa = (int)(fminf(fmaxf(x0f, -2.f), 1217.f)) + 2;
        int xb = (int)(fminf(fmaxf(x0f + 1.f, -2.f), 1217.f)) + 2;
        float v00 = cb[ya * CWP + xa];
        float v01 = cb[ya * CWP + xb];
        float v10 = cb[yb * CWP + xa];
        float v11 = cb[yb * CWP + xb];
        float v = (v00 * (1.f - wx) + v01 * wx) * (1.f - wy)
                + (v10 * (1.f - wx) + v11 * wx) * wy;
        a *= v;
        aff[k] = a;
        asum += fabsf(a);
    }

    float s = fmaxf(asum + 1e-4f, 1.0f);
    float inv = __builtin_amdgcn_rcpf(s);
    float tot = 0.f;
#pragma unroll
    for (int k = 0; k < 8; k++) {
        aff[k] *= inv;
        tot += aff[k];
    }
    float aref = 1.0f - tot;

    // ---- register 5x5 window: separable outer-product accumulation ----
    float w[25];
#pragma unroll
    for (int i = 0; i < 25; i++) w[i] = 0.f;
    bool fits = true;
#pragma unroll
    for (int kk = 0; kk < 9; kk++) {
        float a, dy, dx;
        if (kk < 4)       { a = aff[kk];     dy = ofy[kk];     dx = ofx[kk]; }
        else if (kk == 4) { a = aref;        dy = 0.f;         dx = 0.f; }
        else              { a = aff[kk - 1]; dy = ofy[kk - 1]; dx = ofx[kk - 1]; }
        const int kh = kk / 3 - 1;
        const int kw = kk - (kk / 3) * 3 - 1;
        float fly = floorf(dy), flx = floorf(dx);
        fits = fits && (fly >= -1.f) && (fly <= 0.f)
                    && (flx >= -1.f) && (flx <= 0.f);
        float wy = dy - fly, wx = dx - flx;
        float byf = fly + 1.f, bxf = flx + 1.f;     // in {0,1} on fast path
        int y0 = y + kh + (int)fly;
        int x0 = x + kw + (int)flx;
        float cy0 = (y0 >= 0 && y0 <= HH - 1) ? (1.f - wy) : 0.f;
        float cy1 = (y0 + 1 >= 0 && y0 + 1 <= HH - 1) ? wy : 0.f;
        float cx0 = (x0 >= 0 && x0 <= WW - 1) ? (1.f - wx) : 0.f;
        float cx1 = (x0 + 1 >= 0 && x0 + 1 <= WW - 1) ? wx : 0.f;
        float cya0 = cy0 * a, cya1 = cy1 * a;
        float ry0 = cya0 - byf * cya0;
        float ry1 = fmaf(byf, cya0, cya1 - byf * cya1);
        float ry2 = byf * cya1;
        float rx0 = cx0 - bxf * cx0;
        float rx1 = fmaf(bxf, cx0, cx1 - bxf * cx1);
        float rx2 = bxf * cx1;
        const int base = (kh + 1) * 5 + (kw + 1);   // compile-time
        w[base + 0]  = fmaf(ry0, rx0, w[base + 0]);
        w[base + 1]  = fmaf(ry0, rx1, w[base + 1]);
        w[base + 2]  = fmaf(ry0, rx2, w[base + 2]);
        w[base + 5]  = fmaf(ry1, rx0, w[base + 5]);
        w[base + 6]  = fmaf(ry1, rx1, w[base + 6]);
        w[base + 7]  = fmaf(ry1, rx2, w[base + 7]);
        w[base + 10] = fmaf(ry2, rx0, w[base + 10]);
        w[base + 11] = fmaf(ry2, rx1, w[base + 11]);
        w[base + 12] = fmaf(ry2, rx2, w[base + 12]);
    }

    float yf = (float)y, xf = (float)x;
    if (fits) {
#pragma unroll
        for (int j = 0; j < 13; j++) {
            unsigned lo = f2h(w[2 * j]);
            unsigned hi = (j < 12) ? f2h(w[2 * j + 1]) : 0u;
            Wt[(size_t)j * NPIX + p] = lo | (hi << 16);
        }
    } else {
        int slot = atomicAdd(ovf_cnt, 1);
        unsigned fl = (slot < OVF_CAP) ? (unsigned)(slot + 1) : 65535u;
        if (slot < OVF_CAP) {
            OvfEntry* e = &ovf[slot];
            e->p = p;
#pragma unroll
            for (int kk = 0; kk < 9; kk++) {
                float a, dy, dx;
                if (kk < 4)       { a = aff[kk];     dy = ofy[kk];     dx = ofx[kk]; }
                else if (kk == 4) { a = aref;        dy = 0.f;         dx = 0.f; }
                else              { a = aff[kk - 1]; dy = ofy[kk - 1]; dx = ofx[kk - 1]; }
                float ys = yf + (float)(kk / 3 - 1) + dy;
                float xs = xf + (float)(kk - (kk / 3) * 3 - 1) + dx;
                float y0f = floorf(ys), x0f = floorf(xs);
                float wy = ys - y0f, wx = xs - x0f;
                float y0c = fminf(fmaxf(y0f, -2.f), (float)HH);
                float x0c = fminf(fmaxf(x0f, -2.f), (float)WW);
                int y0 = (int)y0c, x0 = (int)x0c;
                int by = min(max(y0, 0), HH - 2);
                int bx = min(max(x0, 0), WW - 2);
                float cy0 = 0.f, cy1 = 0.f;
                if (y0 >= 0 && y0 <= HH - 1) { if (y0 == by) cy0 = 1.f - wy; else cy1 = 1.f - wy; }
                if (y0 + 1 >= 0 && y0 + 1 <= HH - 1) { if (y0 + 1 == by) cy0 = wy; else cy1 = wy; }
                float cx0 = 0.f, cx1 = 0.f;
                if (x0 >= 0 && x0 <= WW - 1) { if (x0 == bx) cx0 = 1.f - wx; else cx1 = 1.f - wx; }
                if (x0 + 1 >= 0 && x0 + 1 <= WW - 1) { if (x0 + 1 == bx) cx0 = wx; else cx1 = wx; }
                e->base[kk] = (b * HHP + by + 2) * WWP + bx + 2;
                e->w[kk * 4 + 0] = cy0 * cx0 * a;
                e->w[kk * 4 + 1] = cy0 * cx1 * a;
                e->w[kk * 4 + 2] = cy1 * cx0 * a;
                e->w[kk * 4 + 3] = cy1 * cx1 * a;
            }
        }
#pragma unroll
        for (int j = 0; j < 13; j++)
            Wt[(size_t)j * NPIX + p] = (j == 12) ? (fl << 16) : 0u;
    }

    // ---- F0 = sparse-fix-injected initial feat (padded layout) ----
    float ff = feat_fix[p];
    F0[(b * HHP + y + 2) * WWP + x + 2] = (ff > 0.f) ? ff : feat_init[p];
}

// general 9-tap (exception) raw stencil value from padded Fin
__device__ __forceinline__ float general9(const OvfEntry* __restrict__ e,
                                          const float* __restrict__ Fin) {
    float s = 0.f;
#pragma unroll
    for (int kk = 0; kk < 9; kk++) {
        int base = e->base[kk];
        s = fmaf(Fin[base],           e->w[kk * 4 + 0], s);
        s = fmaf(Fin[base + 1],       e->w[kk * 4 + 1], s);
        s = fmaf(Fin[base + WWP],     e->w[kk * 4 + 2], s);
        s = fmaf(Fin[base + WWP + 1], e->w[kk * 4 + 3], s);
    }
    return s;
}

// ---------------------------------------------------------------------------
// One propagation step: dense 5x5 stencil, 4 pixels per thread.
// 13 uint4 Wt loads + 10 float4 window loads per thread (all 16B-aligned).
// ---------------------------------------------------------------------------
__global__ __launch_bounds__(256) void k_prop(
    const float* __restrict__ Fin, const unsigned* __restrict__ Wt,
    const float* __restrict__ feat_fix, const OvfEntry* __restrict__ ovf,
    const int* __restrict__ ovf_cnt, float* __restrict__ Fout, int last) {
    if (blockIdx.x == GRID_PROP) {
        // -------- exception pixels: general 9-tap from global Fin ---------
        int cnt = *ovf_cnt;
        if (cnt > OVF_CAP) cnt = OVF_CAP;
        for (int i = threadIdx.x; i < cnt; i += 256) {
            const OvfEntry* e = &ovf[i];
            float s = general9(e, Fin);
            int p = e->p;
            if (last) {
                Fout[p] = s;
            } else {
                float ff = feat_fix[p];
                int xx = p % WW;
                int yy = (p / WW) % HH;
                int bb = p / NIMG;
                Fout[(bb * HHP + yy + 2) * WWP + xx + 2] = (ff > 0.f) ? ff : s;
            }
        }
        return;
    }

    int t0 = blockIdx.x * 256 + threadIdx.x;
    int p = t0 * 4;                         // quad (p..p+3), same row
    int x = p % WW;
    int y = (p / WW) % HH;
    int b = p / NIMG;
    const float* fb = Fin + (size_t)(b * HHP + y) * WWP + x;

    uint4 u[13];
#pragma unroll
    for (int j = 0; j < 13; j++)
        u[j] = *(const uint4*)&Wt[(size_t)j * NPIX + p];

    float f[5][8];
#pragma unroll
    for (int r = 0; r < 5; r++) {
        const float* row = fb + r * WWP;
        float4 a0 = *(const float4*)(row);
        float4 a1 = *(const float4*)(row + 4);
        f[r][0] = a0.x; f[r][1] = a0.y; f[r][2] = a0.z; f[r][3] = a0.w;
        f[r][4] = a1.x; f[r][5] = a1.y; f[r][6] = a1.z; f[r][7] = a1.w;
    }

    float s0 = 0.f, s1 = 0.f, s2 = 0.f, s3 = 0.f;
#pragma unroll
    for (int c = 0; c < 25; c++) {
        const int j = c >> 1, r = c / 5, cc = c - r * 5;
        unsigned e0 = (c & 1) ? (u[j].x >> 16) : u[j].x;
        unsigned e1 = (c & 1) ? (u[j].y >> 16) : u[j].y;
        unsigned e2 = (c & 1) ? (u[j].z >> 16) : u[j].z;
        unsigned e3 = (c & 1) ? (u[j].w >> 16) : u[j].w;
        s0 = fmaf(f[r][cc],     h2f(e0), s0);
        s1 = fmaf(f[r][cc + 1], h2f(e1), s1);
        s2 = fmaf(f[r][cc + 2], h2f(e2), s2);
        s3 = fmaf(f[r][cc + 3], h2f(e3), s3);
    }
    unsigned fl0 = u[12].x >> 16, fl1 = u[12].y >> 16;
    unsigned fl2 = u[12].z >> 16, fl3 = u[12].w >> 16;
    bool anyflag = (fl0 | fl1 | fl2 | fl3) != 0;

    if (last) {
        if (!anyflag) {
            float4 o = {s0, s1, s2, s3};
            *(float4*)&Fout[p] = o;
        } else {                   // flagged pixels written by exception block
            if (!fl0) Fout[p] = s0;
            if (!fl1) Fout[p + 1] = s1;
            if (!fl2) Fout[p + 2] = s2;
            if (!fl3) Fout[p + 3] = s3;
        }
    } else {
        float4 fix4 = *(const float4*)&feat_fix[p];
        float o0 = (fix4.x > 0.f) ? fix4.x : s0;
        float o1 = (fix4.y > 0.f) ? fix4.y : s1;
        float o2 = (fix4.z > 0.f) ? fix4.z : s2;
        float o3 = (fix4.w > 0.f) ? fix4.w : s3;
        float* po = Fout + (size_t)(b * HHP + y + 2) * WWP + x + 2;
        if (!anyflag) {            // po is 8B-aligned ((x+2)*4 ≡ 8 mod 16)
            float2v w01 = {o0, o1};
            float2v w23 = {o2, o3};
            *(float2v*)(po) = w01;
            *(float2v*)(po + 2) = w23;
        } else {
            if (!fl0) po[0] = o0;
            if (!fl1) po[1] = o1;
            if (!fl2) po[2] = o2;
            if (!fl3) po[3] = o3;
        }
    }
}

extern "C" void kernel_launch(void* const* d_in, const int* in_sizes, int n_in,
                              void* d_out, int out_size, void* d_ws, size_t ws_size,
                              hipStream_t stream) {
    const float* feat_init  = (const float*)d_in[0];
    const float* guidance   = (const float*)d_in[1];
    const float* confidence = (const float*)d_in[2];
    const float* feat_fix   = (const float*)d_in[3];
    const float* W_oa       = (const float*)d_in[4];
    const float* b_oa       = (const float*)d_in[5];
    const float* aff_scale  = (const float*)d_in[6];

    char* ws = (char*)d_ws;
    size_t off = 0;
    auto carve = [&](size_t bytes) -> char* {
        char* ptr = ws + off;
        off += (bytes + 511) & ~(size_t)511;
        return ptr;
    };
    float*    Wre  = (float*)carve(24 * 8 * 9 * sizeof(float));
    float*    CPAD = (float*)carve((size_t)BB * CIMG * sizeof(float));
    float*    F0   = (float*)carve((size_t)BB * PIMG * sizeof(float));
    float*    F1   = (float*)carve((size_t)BB * PIMG * sizeof(float));
    unsigned* Wt   = (unsigned*)carve((size_t)13 * NPIX * sizeof(unsigned));
    OvfEntry* OVF  = (OvfEntry*)carve((size_t)OVF_CAP * sizeof(OvfEntry));
    int*      CNT  = (int*)carve(sizeof(int));
    (void)ws_size; (void)in_sizes; (void)n_in; (void)out_size;

    hipMemsetAsync(CNT, 0, sizeof(int), stream);

    int gridc = (BB * CIMG + 255) / 256;
    hipLaunchKernelGGL(k_permute, dim3(1), dim3(256), 0, stream, W_oa, Wre);
    hipLaunchKernelGGL(k_padconf, dim3(gridc), dim3(256), 0, stream,
                       confidence, CPAD);
    hipLaunchKernelGGL(k_precompute, dim3(GRID_PRE), dim3(256), 0, stream,
                       guidance, CPAD, feat_init, feat_fix, Wre, b_oa,
                       aff_scale, F0, Wt, OVF, CNT);

    float* bufs[2] = {F0, F1};
    int cur = 0;
    for (int it = 0; it < 18; ++it) {
        int last = (it == 17) ? 1 : 0;
        float* outp = last ? (float*)d_out : bufs[cur ^ 1];
        hipLaunchKernelGGL(k_prop, dim3(GRID_PROP + 1), dim3(256), 0, stream,
                           bufs[cur], Wt, feat_fix, OVF, CNT, outp, last);
        cur ^= 1;
    }
}